// Round 3
// baseline (115.762 us; speedup 1.0000x reference)
//
#include <hip/hip_runtime.h>
#include <hip/hip_bf16.h>

// dist[b,c] = ||x_b||^2 + ||p_c||^2 - 2 x_b . p_c
// B=16384, D=512, C=1000 (padded to 1024 in workspace)

#define B_ROWS 16384
#define D_K    512
#define C_COLS 1000
#define C_PAD  1024

#define BM 128
#define BN 128
#define BK 32
#define NK (D_K / BK)  // 16
#define NBUF 4         // 4-deep LDS pipeline, stage 2 K-tiles ahead

typedef __attribute__((ext_vector_type(8))) short short8;
typedef __attribute__((ext_vector_type(4))) float f32x4;

// fp32 -> bf16 round-to-nearest-even
__device__ __forceinline__ unsigned short f2bf(float f) {
  unsigned u = __float_as_uint(f);
  u += 0x7fffu + ((u >> 16) & 1u);
  return (unsigned short)(u >> 16);
}

// 16-byte async global->LDS copy (lane-contiguous LDS destination)
__device__ __forceinline__ void gload16(const void* g, void* l) {
  __builtin_amdgcn_global_load_lds(
      (const __attribute__((address_space(1))) unsigned int*)g,
      (__attribute__((address_space(3))) unsigned int*)l, 16, 0, 0);
}

// One wave per row: cast row to bf16 + fp32 sum of squares.
// Rows [0, B_ROWS) -> x;  rows [B_ROWS, B_ROWS + C_PAD) -> protomat (zero-padded past C_COLS).
__global__ __launch_bounds__(256) void prep_kernel(
    const float* __restrict__ x, const float* __restrict__ p,
    unsigned short* __restrict__ xb, unsigned short* __restrict__ pb,
    float* __restrict__ xsq, float* __restrict__ psq) {
  const int wave = threadIdx.x >> 6;
  const int lane = threadIdx.x & 63;
  const int row  = blockIdx.x * 4 + wave;
  const bool isx = row < B_ROWS;
  const int r2   = isx ? row : row - B_ROWS;

  float v[8];
  if (isx) {
    const float4* s = reinterpret_cast<const float4*>(x + (size_t)r2 * D_K + lane * 8);
    float4 a = s[0], b = s[1];
    v[0] = a.x; v[1] = a.y; v[2] = a.z; v[3] = a.w;
    v[4] = b.x; v[5] = b.y; v[6] = b.z; v[7] = b.w;
  } else if (r2 < C_COLS) {
    const float4* s = reinterpret_cast<const float4*>(p + (size_t)r2 * D_K + lane * 8);
    float4 a = s[0], b = s[1];
    v[0] = a.x; v[1] = a.y; v[2] = a.z; v[3] = a.w;
    v[4] = b.x; v[5] = b.y; v[6] = b.z; v[7] = b.w;
  } else {
#pragma unroll
    for (int j = 0; j < 8; ++j) v[j] = 0.0f;
  }

  float ss = 0.0f;
  unsigned short u[8];
#pragma unroll
  for (int j = 0; j < 8; ++j) { ss += v[j] * v[j]; u[j] = f2bf(v[j]); }

  uint4 pk;
  pk.x = (unsigned)u[0] | ((unsigned)u[1] << 16);
  pk.y = (unsigned)u[2] | ((unsigned)u[3] << 16);
  pk.z = (unsigned)u[4] | ((unsigned)u[5] << 16);
  pk.w = (unsigned)u[6] | ((unsigned)u[7] << 16);
  unsigned short* dst = (isx ? xb : pb) + (size_t)r2 * D_K + lane * 8;
  *reinterpret_cast<uint4*>(dst) = pk;

#pragma unroll
  for (int off = 32; off > 0; off >>= 1) ss += __shfl_down(ss, off);
  if (lane == 0) (isx ? xsq : psq)[r2] = ss;
}

// 128x128 tile, BK=32, 4 waves (2x2), 4-deep LDS pipeline with counted
// vmcnt (stage 2 K-tiles ahead, never drain to 0 mid-loop), chunk-permuted
// LDS layout (bank-conflict-free ds_read_b128), XCD-aware block swizzle,
// 16x16x32 bf16 MFMA, fused distance epilogue.
//
// LDS layout: tile stored as 512 chunks of 16B. Fragment (row, kslot)
// lives at chunk idx(row, kslot) = row*4 + ((kslot + (row>>1)) & 3).
// Staging chunk ch loads global k-group ((ch&3) - ((ch>>2)>>1)) & 3.
//
// Pipeline safety: STAGE(t+2) writes buf[(t+2)&3] = buf[(t-2)&3], last read
// by COMPUTE(t-2); iteration (t-1)'s s_barrier sits between them in every
// wave's program order -> no WAR race. vmcnt(8) before the barrier leaves
// tiles t+1,t+2 (4 loads each) in flight and guarantees tile t landed;
// every wave waits its own loads, the barrier makes it collective.
__global__ __launch_bounds__(256, 2) void gemm_kernel(
    const unsigned short* __restrict__ xb, const unsigned short* __restrict__ pb,
    const float* __restrict__ xsq, const float* __restrict__ psq,
    float* __restrict__ out) {
  __shared__ __align__(16) unsigned short As[NBUF][BM * BK];  // 4 x 8 KiB
  __shared__ __align__(16) unsigned short Bs[NBUF][BN * BK];  // 4 x 8 KiB

  const int tid  = threadIdx.x;
  const int lane = tid & 63;
  const int wave = tid >> 6;
  const int wr   = wave >> 1;
  const int wc   = wave & 1;

  // XCD-aware swizzle: XCD x gets bm in [x*16, x*16+16), all bn.
  const int bid = blockIdx.x;
  const int tt  = (bid & 7) * 128 + (bid >> 3);
  const int bm  = tt >> 3;  // 0..127
  const int bn  = tt & 7;   // 0..7

  // Staging: chunk ch -> row = ch>>2, permuted global k-group.
  const int ch0 = tid;
  const int ch1 = tid + 256;
  const int r0  = ch0 >> 2, r1 = ch1 >> 2;
  const int kg0 = ((ch0 & 3) - (r0 >> 1)) & 3;
  const int kg1 = ((ch1 & 3) - (r1 >> 1)) & 3;
  const unsigned short* a0 = xb + ((size_t)bm * BM + r0) * D_K + kg0 * 8;
  const unsigned short* a1 = xb + ((size_t)bm * BM + r1) * D_K + kg1 * 8;
  const unsigned short* b0 = pb + ((size_t)bn * BN + r0) * D_K + kg0 * 8;
  const unsigned short* b1 = pb + ((size_t)bn * BN + r1) * D_K + kg1 * 8;

  f32x4 acc[4][4];
#pragma unroll
  for (int i = 0; i < 4; ++i)
#pragma unroll
    for (int j = 0; j < 4; ++j) acc[i][j] = (f32x4){0.f, 0.f, 0.f, 0.f};

  const int mrow = wr * 64 + (lane & 15);
  const int ncol = wc * 64 + (lane & 15);
  // Permuted read position for wanted kslot = lane>>4.
  const int pslot = (((lane >> 4) + ((lane & 15) >> 1)) & 3);
  const int koffb = pslot * 8;

#define STAGE(T, BUF)                                   \
  do {                                                  \
    const int ko = (T)*BK;                              \
    gload16(a0 + ko, &As[BUF][ch0 * 8]);                \
    gload16(a1 + ko, &As[BUF][ch1 * 8]);                \
    gload16(b0 + ko, &Bs[BUF][ch0 * 8]);                \
    gload16(b1 + ko, &Bs[BUF][ch1 * 8]);                \
  } while (0)

#define COMPUTE(BUF)                                                          \
  do {                                                                        \
    short8 af[4], bfr[4];                                                     \
    _Pragma("unroll") for (int i = 0; i < 4; ++i)                             \
        af[i] = *reinterpret_cast<const short8*>(                             \
            &As[BUF][(mrow + i * 16) * BK + koffb]);                          \
    _Pragma("unroll") for (int j = 0; j < 4; ++j)                             \
        bfr[j] = *reinterpret_cast<const short8*>(                            \
            &Bs[BUF][(ncol + j * 16) * BK + koffb]);                          \
    _Pragma("unroll") for (int i = 0; i < 4; ++i)                             \
        _Pragma("unroll") for (int j = 0; j < 4; ++j)                         \
            acc[i][j] = __builtin_amdgcn_mfma_f32_16x16x32_bf16(              \
                af[i], bfr[j], acc[i][j], 0, 0, 0);                           \
  } while (0)

  STAGE(0, 0);
  STAGE(1, 1);

  for (int t = 0; t < NK - 2; ++t) {
    STAGE(t + 2, (t + 2) & 3);
    asm volatile("s_waitcnt vmcnt(8)" ::: "memory");  // tile t landed; t+1,t+2 in flight
    __builtin_amdgcn_s_barrier();
    COMPUTE(t & 3);
  }
  // t = NK-2: tiles NK-2, NK-1 outstanding (8 loads) -> need NK-2 done
  asm volatile("s_waitcnt vmcnt(4)" ::: "memory");
  __builtin_amdgcn_s_barrier();
  COMPUTE((NK - 2) & 3);
  // t = NK-1: drain
  asm volatile("s_waitcnt vmcnt(0)" ::: "memory");
  __builtin_amdgcn_s_barrier();
  COMPUTE((NK - 1) & 3);

#undef STAGE
#undef COMPUTE

  // Epilogue: out[b][c] = xsq[b] + psq[c] - 2*cross
  const int colbase = bn * BN + wc * 64 + (lane & 15);
  float pc[4];
#pragma unroll
  for (int j = 0; j < 4; ++j) pc[j] = psq[colbase + j * 16];  // C_PAD-sized: in bounds

  const int rowbase = bm * BM + wr * 64 + ((lane >> 4) << 2);
#pragma unroll
  for (int i = 0; i < 4; ++i) {
#pragma unroll
    for (int r = 0; r < 4; ++r) {
      const int row = rowbase + i * 16 + r;
      const float xs = xsq[row];
#pragma unroll
      for (int j = 0; j < 4; ++j) {
        const int c = colbase + j * 16;
        if (c < C_COLS)
          out[(size_t)row * C_COLS + c] = xs + pc[j] - 2.0f * acc[i][j][r];
      }
    }
  }
}

extern "C" void kernel_launch(void* const* d_in, const int* in_sizes, int n_in,
                              void* d_out, int out_size, void* d_ws, size_t ws_size,
                              hipStream_t stream) {
  const float* x = (const float*)d_in[0];
  const float* p = (const float*)d_in[1];
  float* out = (float*)d_out;

  char* ws = (char*)d_ws;
  unsigned short* xb  = (unsigned short*)ws;                        // 16384*512*2 = 16 MiB
  unsigned short* pb  = (unsigned short*)(ws + 16777216);           // 1024*512*2  = 1 MiB
  float* xsq          = (float*)(ws + 16777216 + 1048576);          // 64 KiB
  float* psq          = (float*)(ws + 16777216 + 1048576 + 65536);  // 4 KiB

  // Prep: one wave per row, (16384 + 1024) rows / 4 waves per block
  prep_kernel<<<(B_ROWS + C_PAD) / 4, 256, 0, stream>>>(x, p, xb, pb, xsq, psq);

  // GEMM: 1024 blocks, XCD-swizzled in-kernel
  gemm_kernel<<<1024, 256, 0, stream>>>(xb, pb, xsq, psq, out);
}

// Round 5
// 111.071 us; speedup vs baseline: 1.0422x; 1.0422x over previous
//
#include <hip/hip_runtime.h>
#include <hip/hip_bf16.h>

// dist[b,c] = ||x_b||^2 + ||p_c||^2 - 2 x_b . p_c
// B=16384, D=512, C=1000 (padded to 1024 in workspace)

#define B_ROWS 16384
#define D_K    512
#define C_COLS 1000
#define C_PAD  1024

#define BM 256
#define BN 256
#define BK 32
#define NK (D_K / BK)  // 16
#define NBUF 4         // 4-deep LDS pipeline, stage 3 K-tiles ahead
#define TILE_SH 16384  // ushort elems per buffer (A 8192 + B 8192)

typedef __attribute__((ext_vector_type(8))) short short8;
typedef __attribute__((ext_vector_type(4))) float f32x4;

// fp32 -> bf16 round-to-nearest-even
__device__ __forceinline__ unsigned short f2bf(float f) {
  unsigned u = __float_as_uint(f);
  u += 0x7fffu + ((u >> 16) & 1u);
  return (unsigned short)(u >> 16);
}

// 16-byte async global->LDS copy (lane-contiguous LDS destination)
__device__ __forceinline__ void gload16(const void* g, void* l) {
  __builtin_amdgcn_global_load_lds(
      (const __attribute__((address_space(1))) unsigned int*)g,
      (__attribute__((address_space(3))) unsigned int*)l, 16, 0, 0);
}

// One wave per row: cast row to bf16 + fp32 sum of squares.
// Rows [0, B_ROWS) -> x;  rows [B_ROWS, B_ROWS + C_PAD) -> protomat (zero-padded past C_COLS).
__global__ __launch_bounds__(256) void prep_kernel(
    const float* __restrict__ x, const float* __restrict__ p,
    unsigned short* __restrict__ xb, unsigned short* __restrict__ pb,
    float* __restrict__ xsq, float* __restrict__ psq) {
  const int wave = threadIdx.x >> 6;
  const int lane = threadIdx.x & 63;
  const int row  = blockIdx.x * 4 + wave;
  const bool isx = row < B_ROWS;
  const int r2   = isx ? row : row - B_ROWS;

  float v[8];
  if (isx) {
    const float4* s = reinterpret_cast<const float4*>(x + (size_t)r2 * D_K + lane * 8);
    float4 a = s[0], b = s[1];
    v[0] = a.x; v[1] = a.y; v[2] = a.z; v[3] = a.w;
    v[4] = b.x; v[5] = b.y; v[6] = b.z; v[7] = b.w;
  } else if (r2 < C_COLS) {
    const float4* s = reinterpret_cast<const float4*>(p + (size_t)r2 * D_K + lane * 8);
    float4 a = s[0], b = s[1];
    v[0] = a.x; v[1] = a.y; v[2] = a.z; v[3] = a.w;
    v[4] = b.x; v[5] = b.y; v[6] = b.z; v[7] = b.w;
  } else {
#pragma unroll
    for (int j = 0; j < 8; ++j) v[j] = 0.0f;
  }

  float ss = 0.0f;
  unsigned short u[8];
#pragma unroll
  for (int j = 0; j < 8; ++j) { ss += v[j] * v[j]; u[j] = f2bf(v[j]); }

  uint4 pk;
  pk.x = (unsigned)u[0] | ((unsigned)u[1] << 16);
  pk.y = (unsigned)u[2] | ((unsigned)u[3] << 16);
  pk.z = (unsigned)u[4] | ((unsigned)u[5] << 16);
  pk.w = (unsigned)u[6] | ((unsigned)u[7] << 16);
  unsigned short* dst = (isx ? xb : pb) + (size_t)r2 * D_K + lane * 8;
  *reinterpret_cast<uint4*>(dst) = pk;

#pragma unroll
  for (int off = 32; off > 0; off >>= 1) ss += __shfl_down(ss, off);
  if (lane == 0) (isx ? xsq : psq)[r2] = ss;
}

// 256x256 tile, BK=32, 8 waves (2M x 4N, 128x64 per wave), 4-deep LDS
// pipeline with counted vmcnt (stage 3 ahead, never drain mid-loop),
// chunk-permuted conflict-free LDS, XCD swizzle, setprio around MFMA,
// fused distance epilogue.
//
// LDS per buffer: A-tile 8192 ushort (256 rows x 32k), B-tile 8192.
// Chunk layout: fragment (row, kslot) at chunk row*4 + ((kslot + (row>>1)) & 3).
// ds_read addr: p = ((lane>>4) + ((lane&15)>>1)) & 3 is m/n-invariant (m*8 = 0 mod 4),
// so frag m sits at base + m*512 elems (compile-time offset).
//
// Iteration t: vmcnt(8) -> s_barrier -> STAGE(t+3 -> buf[(t-1)&3]) -> COMPUTE(t).
// STAGE comes after the barrier, so buf[(t-1)&3]'s readers (COMPUTE(t-1), all
// waves) have passed it -> no WAR race. vmcnt(8) = tiles t+1,t+2 in flight
// (4 loads/thread each); tile t is guaranteed landed. Tail: 8/8/4/0.
__global__ __launch_bounds__(512, 2) void gemm_kernel(
    const unsigned short* __restrict__ xb, const unsigned short* __restrict__ pb,
    const float* __restrict__ xsq, const float* __restrict__ psq,
    float* __restrict__ out) {
  __shared__ __align__(16) unsigned short L[NBUF * TILE_SH];  // 128 KiB

  const int tid  = threadIdx.x;
  const int lane = tid & 63;
  const int wave = tid >> 6;
  const int wm   = wave >> 2;  // 0..1
  const int wn   = wave & 3;   // 0..3

  // XCD swizzle: 256 blocks; XCD x gets bm in [x*8, x*8+8), all 4 bn.
  const int bid = blockIdx.x;
  const int tt  = (bid & 7) * 32 + (bid >> 3);
  const int bm  = tt >> 2;  // 0..63
  const int bn  = tt & 3;   // 0..3

  // Staging: chunks tid, tid+512 for A and for B. row = ch>>2, stored pos = ch&3,
  // global k-group ks = (pos - (row>>1)) & 3.
  const int chA0 = tid, chA1 = tid + 512;
  const int rA0 = chA0 >> 2, rA1 = chA1 >> 2;
  const int ksA0 = ((chA0 & 3) - (rA0 >> 1)) & 3;
  const int ksA1 = ((chA1 & 3) - (rA1 >> 1)) & 3;
  const unsigned short* gA0 = xb + ((size_t)bm * BM + rA0) * D_K + ksA0 * 8;
  const unsigned short* gA1 = xb + ((size_t)bm * BM + rA1) * D_K + ksA1 * 8;
  const unsigned short* gB0 = pb + ((size_t)bn * BN + rA0) * D_K + ksA0 * 8;
  const unsigned short* gB1 = pb + ((size_t)bn * BN + rA1) * D_K + ksA1 * 8;
  unsigned short* lA0 = &L[chA0 * 8];
  unsigned short* lA1 = &L[chA1 * 8];
  unsigned short* lB0 = &L[8192 + chA0 * 8];
  unsigned short* lB1 = &L[8192 + chA1 * 8];

  f32x4 acc[8][4];
#pragma unroll
  for (int m = 0; m < 8; ++m)
#pragma unroll
    for (int n = 0; n < 4; ++n) acc[m][n] = (f32x4){0.f, 0.f, 0.f, 0.f};

  // ds_read bases (ushort elems). p-slot: permuted position of kslot lane>>4.
  const int l15 = lane & 15;
  const int pos = (((lane >> 4) + (l15 >> 1)) & 3);
  const int rdA = (wm * 128 + l15) * 32 + pos * 8;         // + m*512 per frag
  const int rdB = 8192 + (wn * 64 + l15) * 32 + pos * 8;   // + n*512 per frag

#define STAGE(T, BUF)                                     \
  do {                                                    \
    const int ko = (T)*BK;                                \
    const int bo = (BUF)*TILE_SH;                         \
    gload16(gA0 + ko, lA0 + bo);                          \
    gload16(gA1 + ko, lA1 + bo);                          \
    gload16(gB0 + ko, lB0 + bo);                          \
    gload16(gB1 + ko, lB1 + bo);                          \
  } while (0)

#define COMPUTE(BUF)                                                          \
  do {                                                                        \
    const unsigned short* Ab = &L[(BUF)*TILE_SH] + rdA;                       \
    const unsigned short* Bb = &L[(BUF)*TILE_SH] + rdB;                       \
    short8 bfr[4];                                                            \
    _Pragma("unroll") for (int n = 0; n < 4; ++n)                             \
        bfr[n] = *reinterpret_cast<const short8*>(Bb + n * 512);              \
    __builtin_amdgcn_s_setprio(1);                                            \
    _Pragma("unroll") for (int m = 0; m < 8; ++m) {                           \
      short8 af = *reinterpret_cast<const short8*>(Ab + m * 512);             \
      _Pragma("unroll") for (int n = 0; n < 4; ++n)                           \
          acc[m][n] = __builtin_amdgcn_mfma_f32_16x16x32_bf16(                \
              af, bfr[n], acc[m][n], 0, 0, 0);                                \
    }                                                                         \
    __builtin_amdgcn_s_setprio(0);                                            \
  } while (0)

  STAGE(0, 0);
  STAGE(1, 1);
  STAGE(2, 2);

#pragma unroll 1
  for (int t = 0; t < NK - 3; ++t) {  // t = 0..12
    asm volatile("s_waitcnt vmcnt(8)" ::: "memory");  // tile t landed; t+1,t+2 in flight
    __builtin_amdgcn_s_barrier();
    STAGE(t + 3, (t + 3) & 3);  // writes buf[(t-1)&3]: readers passed barrier above
    COMPUTE(t & 3);
  }
  asm volatile("s_waitcnt vmcnt(8)" ::: "memory");  // tiles 14,15 in flight
  __builtin_amdgcn_s_barrier();
  COMPUTE(13 & 3);
  asm volatile("s_waitcnt vmcnt(4)" ::: "memory");  // tile 15 in flight
  __builtin_amdgcn_s_barrier();
  COMPUTE(14 & 3);
  asm volatile("s_waitcnt vmcnt(0)" ::: "memory");
  __builtin_amdgcn_s_barrier();
  COMPUTE(15 & 3);

#undef STAGE
#undef COMPUTE

  // Epilogue: out[b][c] = xsq[b] + psq[c] - 2*cross
  const int colb = bn * BN + wn * 64 + l15;
  float pc[4];
#pragma unroll
  for (int n = 0; n < 4; ++n) pc[n] = psq[colb + n * 16];  // C_PAD-sized: in bounds

  const int rowb = bm * BM + wm * 128 + ((lane >> 4) << 2);
#pragma unroll
  for (int m = 0; m < 8; ++m) {
#pragma unroll
    for (int r = 0; r < 4; ++r) {
      const int row = rowb + m * 16 + r;
      const float xs = xsq[row];
#pragma unroll
      for (int n = 0; n < 4; ++n) {
        const int c = colb + n * 16;
        if (c < C_COLS)
          out[(size_t)row * C_COLS + c] = xs + pc[n] - 2.0f * acc[m][n][r];
      }
    }
  }
}

extern "C" void kernel_launch(void* const* d_in, const int* in_sizes, int n_in,
                              void* d_out, int out_size, void* d_ws, size_t ws_size,
                              hipStream_t stream) {
  const float* x = (const float*)d_in[0];
  const float* p = (const float*)d_in[1];
  float* out = (float*)d_out;

  char* ws = (char*)d_ws;
  unsigned short* xb  = (unsigned short*)ws;                        // 16384*512*2 = 16 MiB
  unsigned short* pb  = (unsigned short*)(ws + 16777216);           // 1024*512*2  = 1 MiB
  float* xsq          = (float*)(ws + 16777216 + 1048576);          // 64 KiB
  float* psq          = (float*)(ws + 16777216 + 1048576 + 65536);  // 4 KiB

  // Prep: one wave per row, (16384 + 1024) rows / 4 waves per block
  prep_kernel<<<(B_ROWS + C_PAD) / 4, 256, 0, stream>>>(x, p, xb, pb, xsq, psq);

  // GEMM: 256 blocks (64 bm x 4 bn), XCD-swizzled in-kernel, 512 threads
  gemm_kernel<<<256, 512, 0, stream>>>(xb, pb, xsq, psq, out);
}